// Round 1
// baseline (2543.579 us; speedup 1.0000x reference)
//
#include <hip/hip_runtime.h>
#include <hip/hip_bf16.h>
#include <stdint.h>

// Problem constants (B, Lq, Lk, D) from reference setup_inputs()
#define NB  16
#define LQ  1024
#define LK  2048
#define DIM 4096

typedef __attribute__((ext_vector_type(4))) float f32x4;
typedef __attribute__((ext_vector_type(8))) short bf16x8;
typedef __attribute__((ext_vector_type(4))) short bf16x4;

__device__ __forceinline__ unsigned short f2bf_rne(float f) {
  union { float f; unsigned int u; } v; v.f = f;
  unsigned int r = (v.u + 0x7fffu + ((v.u >> 16) & 1u)) >> 16;
  return (unsigned short)r;
}
__device__ __forceinline__ float bf2f(unsigned short h) {
  union { float f; unsigned int u; } v; v.u = ((unsigned int)h) << 16;
  return v.f;
}

// -------------------------------------------------------------------------
// Kernel 1: S[b,q,k] = sum_d Q[b,q,d] * K[b,k,d]   (both contraction-contiguous)
// 3-term bf16 split for ~fp32 accuracy: S = Qh*Kh + Qh*Kl + Ql*Kh
// 128x128 tile, BK=32, 256 threads (4 waves, 2x2, each 64x64 = 4x4 mfma tiles)
// LDS rows padded 32->40 bf16 (keeps 16B alignment for ds_read_b128).
// -------------------------------------------------------------------------
__global__ __launch_bounds__(256, 1) void gemm_qk_split(
    const float* __restrict__ Q, const float* __restrict__ K,
    float* __restrict__ S) {
  __shared__ unsigned short Ah[128 * 40];
  __shared__ unsigned short Al[128 * 40];
  __shared__ unsigned short Bh[128 * 40];
  __shared__ unsigned short Bl[128 * 40];

  const int b  = blockIdx.y;
  const int qi = blockIdx.x & 7;    // 8 M-tiles
  const int ni = blockIdx.x >> 3;   // 16 N-tiles
  const int q0 = qi * 128, n0 = ni * 128;

  const int t    = threadIdx.x;
  const int lane = t & 63, w = t >> 6;
  const int wm = w >> 1, wn = w & 1;
  const int lm = lane & 15, lk = (lane >> 4) * 8;

  const float* Qb = Q + ((size_t)b * LQ + q0) * DIM;
  const float* Kb = K + ((size_t)b * LK + n0) * DIM;

  f32x4 acc[4][4] = {};

  for (int kt = 0; kt < DIM / 32; ++kt) {
    const int k0 = kt * 32;
    // prefetch global into regs (128x32 floats per tile; 4 float4 per thread)
    f32x4 qa[4], kb[4];
#pragma unroll
    for (int i = 0; i < 4; ++i) {
      const int f = i * 256 + t;
      const int row = f >> 3, c4 = f & 7;
      qa[i] = *(const f32x4*)(Qb + (size_t)row * DIM + k0 + c4 * 4);
      kb[i] = *(const f32x4*)(Kb + (size_t)row * DIM + k0 + c4 * 4);
    }
    __syncthreads();  // prior iteration's fragment reads complete
#pragma unroll
    for (int i = 0; i < 4; ++i) {
      const int f = i * 256 + t;
      const int row = f >> 3, c4 = f & 7;
      bf16x4 qh, ql, kh, kl;
#pragma unroll
      for (int j = 0; j < 4; ++j) {
        float x = qa[i][j];
        unsigned short h = f2bf_rne(x);
        qh[j] = (short)h;
        ql[j] = (short)f2bf_rne(x - bf2f(h));
        float y = kb[i][j];
        unsigned short h2 = f2bf_rne(y);
        kh[j] = (short)h2;
        kl[j] = (short)f2bf_rne(y - bf2f(h2));
      }
      const int a = row * 40 + c4 * 4;
      *(bf16x4*)&Ah[a] = qh;
      *(bf16x4*)&Al[a] = ql;
      *(bf16x4*)&Bh[a] = kh;
      *(bf16x4*)&Bl[a] = kl;
    }
    __syncthreads();

    bf16x8 fah[4], fal[4], fbh[4], fbl[4];
#pragma unroll
    for (int m = 0; m < 4; ++m) {
      const int r = (wm * 64 + m * 16 + lm) * 40 + lk;
      fah[m] = *(const bf16x8*)&Ah[r];
      fal[m] = *(const bf16x8*)&Al[r];
    }
#pragma unroll
    for (int n = 0; n < 4; ++n) {
      const int r = (wn * 64 + n * 16 + lm) * 40 + lk;
      fbh[n] = *(const bf16x8*)&Bh[r];
      fbl[n] = *(const bf16x8*)&Bl[r];
    }
#pragma unroll
    for (int m = 0; m < 4; ++m)
#pragma unroll
      for (int n = 0; n < 4; ++n) {
        acc[m][n] = __builtin_amdgcn_mfma_f32_16x16x32_bf16(fah[m], fbh[n], acc[m][n], 0, 0, 0);
        acc[m][n] = __builtin_amdgcn_mfma_f32_16x16x32_bf16(fah[m], fbl[n], acc[m][n], 0, 0, 0);
        acc[m][n] = __builtin_amdgcn_mfma_f32_16x16x32_bf16(fal[m], fbh[n], acc[m][n], 0, 0, 0);
      }
  }

  // C/D layout (verified m89/m91): col = lane&15, row = (lane>>4)*4 + reg
  float* Sb = S + (size_t)b * LQ * LK;
  const int rq = (lane >> 4) * 4, cl = lane & 15;
#pragma unroll
  for (int m = 0; m < 4; ++m) {
    const int grow = q0 + wm * 64 + m * 16 + rq;
#pragma unroll
    for (int n = 0; n < 4; ++n) {
      const int gcol = n0 + wn * 64 + n * 16 + cl;
      f32x4 v = acc[m][n];
#pragma unroll
      for (int r = 0; r < 4; ++r)
        Sb[(size_t)(grow + r) * LK + gcol] = v[r];
    }
  }
}

// -------------------------------------------------------------------------
// Kernel 2: in-place row softmax over Lk=2048. One block (256 thr) per row.
// fp32 exact (subtract max), logits can be ~±300 so max-subtraction required.
// -------------------------------------------------------------------------
__global__ __launch_bounds__(256, 1) void softmax_rows(float* __restrict__ S) {
  const int row = blockIdx.x;  // NB*LQ = 16384 rows
  float* p = S + (size_t)row * LK;
  const int t = threadIdx.x;
  const int lane = t & 63, w = t >> 6;

  f32x4 x0 = *(const f32x4*)(p + t * 4);
  f32x4 x1 = *(const f32x4*)(p + 1024 + t * 4);

  float m = -INFINITY;
#pragma unroll
  for (int j = 0; j < 4; ++j) {
    m = fmaxf(m, x0[j]);
    m = fmaxf(m, x1[j]);
  }
#pragma unroll
  for (int off = 32; off > 0; off >>= 1) m = fmaxf(m, __shfl_xor(m, off));
  __shared__ float redm[4];
  if (lane == 0) redm[w] = m;
  __syncthreads();
  m = fmaxf(fmaxf(redm[0], redm[1]), fmaxf(redm[2], redm[3]));

  float s = 0.f;
#pragma unroll
  for (int j = 0; j < 4; ++j) {
    x0[j] = __expf(x0[j] - m);
    s += x0[j];
    x1[j] = __expf(x1[j] - m);
    s += x1[j];
  }
#pragma unroll
  for (int off = 32; off > 0; off >>= 1) s += __shfl_xor(s, off);
  __shared__ float reds[4];
  if (lane == 0) reds[w] = s;
  __syncthreads();
  s = reds[0] + reds[1] + reds[2] + reds[3];

  const float inv = 1.f / s;
#pragma unroll
  for (int j = 0; j < 4; ++j) {
    x0[j] *= inv;
    x1[j] *= inv;
  }
  *(f32x4*)(p + t * 4) = x0;
  *(f32x4*)(p + 1024 + t * 4) = x1;
}

// -------------------------------------------------------------------------
// Kernel 3: C[b,q,d] = sum_k P[b,q,k] * K[b,k,d]   (plain bf16)
// A = P (contraction-contiguous). B = K needs transposed LDS tile Bt[d][k]:
// staged via coalesced scalar loads along d (8 k's per thread at fixed d),
// then one ds_write_b128 per 8-k group. Rows padded 32->40.
// -------------------------------------------------------------------------
__global__ __launch_bounds__(256, 1) void gemm_pv(
    const float* __restrict__ P, const float* __restrict__ K,
    float* __restrict__ C) {
  __shared__ unsigned short Pa[128 * 40];
  __shared__ unsigned short Bt[128 * 40];

  const int b  = blockIdx.y;
  const int qi = blockIdx.x & 7;    // 8 M-tiles (q)
  const int di = blockIdx.x >> 3;   // 32 N-tiles (d)
  const int q0 = qi * 128, d0 = di * 128;

  const int t    = threadIdx.x;
  const int lane = t & 63, w = t >> 6;
  const int wm = w >> 1, wn = w & 1;
  const int lm = lane & 15, lk = (lane >> 4) * 8;

  const float* Pb = P + ((size_t)b * LQ + q0) * LK;
  const float* Kb = K + (size_t)b * LK * DIM + d0;

  const int td = t & 127, toct = t >> 7;  // d-col, base k-octet

  f32x4 acc[4][4] = {};

  for (int kt = 0; kt < LK / 32; ++kt) {
    const int k0 = kt * 32;
    // A prefetch: P tile 128x32 floats
    f32x4 pa[4];
#pragma unroll
    for (int i = 0; i < 4; ++i) {
      const int f = i * 256 + t;
      const int row = f >> 3, c4 = f & 7;
      pa[i] = *(const f32x4*)(Pb + (size_t)row * LK + k0 + c4 * 4);
    }
    // B prefetch: K tile 32x128, gathered transposed (8 k's per thread, 2 octets)
    float kv[2][8];
#pragma unroll
    for (int o = 0; o < 2; ++o) {
      const int octf = 2 * o + toct;
#pragma unroll
      for (int j = 0; j < 8; ++j)
        kv[o][j] = Kb[(size_t)(k0 + octf * 8 + j) * DIM + td];
    }
    __syncthreads();
#pragma unroll
    for (int i = 0; i < 4; ++i) {
      const int f = i * 256 + t;
      const int row = f >> 3, c4 = f & 7;
      bf16x4 ph;
#pragma unroll
      for (int j = 0; j < 4; ++j) ph[j] = (short)f2bf_rne(pa[i][j]);
      *(bf16x4*)&Pa[row * 40 + c4 * 4] = ph;
    }
#pragma unroll
    for (int o = 0; o < 2; ++o) {
      const int octf = 2 * o + toct;
      bf16x8 kb8;
#pragma unroll
      for (int j = 0; j < 8; ++j) kb8[j] = (short)f2bf_rne(kv[o][j]);
      *(bf16x8*)&Bt[td * 40 + octf * 8] = kb8;
    }
    __syncthreads();

    bf16x8 fa[4], fb[4];
#pragma unroll
    for (int m = 0; m < 4; ++m)
      fa[m] = *(const bf16x8*)&Pa[(wm * 64 + m * 16 + lm) * 40 + lk];
#pragma unroll
    for (int n = 0; n < 4; ++n)
      fb[n] = *(const bf16x8*)&Bt[(wn * 64 + n * 16 + lm) * 40 + lk];
#pragma unroll
    for (int m = 0; m < 4; ++m)
#pragma unroll
      for (int n = 0; n < 4; ++n)
        acc[m][n] = __builtin_amdgcn_mfma_f32_16x16x32_bf16(fa[m], fb[n], acc[m][n], 0, 0, 0);
  }

  float* Cb = C + (size_t)b * LQ * DIM;
  const int rq = (lane >> 4) * 4, cl = lane & 15;
#pragma unroll
  for (int m = 0; m < 4; ++m) {
    const int grow = q0 + wm * 64 + m * 16 + rq;
#pragma unroll
    for (int n = 0; n < 4; ++n) {
      const int gcol = d0 + wn * 64 + n * 16 + cl;
      f32x4 v = acc[m][n];
#pragma unroll
      for (int r = 0; r < 4; ++r)
        Cb[(size_t)(grow + r) * DIM + gcol] = v[r];
    }
  }
}

extern "C" void kernel_launch(void* const* d_in, const int* in_sizes, int n_in,
                              void* d_out, int out_size, void* d_ws, size_t ws_size,
                              hipStream_t stream) {
  const float* Q = (const float*)d_in[0];
  const float* K = (const float*)d_in[1];
  float* C = (float*)d_out;
  float* S = (float*)d_ws;  // needs NB*LQ*LK*4 = 128 MiB scratch

  dim3 blk(256);
  // batch on grid.y so same-batch tiles are dispatched together (LLC reuse)
  gemm_qk_split<<<dim3(8 * 16, NB), blk, 0, stream>>>(Q, K, S);
  softmax_rows<<<dim3(NB * LQ), blk, 0, stream>>>(S);
  gemm_pv<<<dim3(8 * 32, NB), blk, 0, stream>>>(S, K, C);
}